// Round 2
// baseline (144.081 us; speedup 1.0000x reference)
//
#include <hip/hip_runtime.h>

#define NB   8
#define NDEP 64
#define KK   512
#define NP   12
#define NT   550
#define NGN  2   // n's per block -> 8*32 = 256 blocks

__global__ __launch_bounds__(256) void next_sim_kernel(
    const float* __restrict__ ed,      // (8,64,4) x,y,z,E
    const float* __restrict__ edraw,   // (8,64)
    const float* __restrict__ ddraw,   // (8,64,512,3)
    const float* __restrict__ udraw,   // (8,64,512)
    const float* __restrict__ W1,      // (2,28)
    const float* __restrict__ b1,      // (28)
    const float* __restrict__ W2,      // (28,12)
    const float* __restrict__ b2,      // (12)
    const float* __restrict__ dscale,  // (3)
    const float* __restrict__ pscale,  // (12)
    const float* __restrict__ life,    // (1)
    float* __restrict__ out)           // (8,12,550)
{
    __shared__ float acc[NT * NP];               // [t][p], 26400 B
    __shared__ float sW1[56], sb1[28], sW2[336], sb2[12], sS2[12], sD2[3];

    const int tid = threadIdx.x;
    const int bid = blockIdx.x;
    const int b   = bid / (NDEP / NGN);
    const int n0  = (bid % (NDEP / NGN)) * NGN;

    for (int i = tid; i < NT * NP; i += 256) acc[i] = 0.0f;
    for (int i = tid; i < 336; i += 256) sW2[i] = W2[i];
    if (tid < 56) sW1[tid] = W1[tid];
    if (tid < 28) sb1[tid] = b1[tid];
    if (tid < 12) sb2[tid] = b2[tid];
    if (tid < 12) { float s = pscale[tid]; sS2[tid] = s * s; }
    if (tid < 3)  { float s = dscale[tid]; sD2[tid] = s * s; }
    __syncthreads();

    const float invLife = 1.0f / life[0];

    for (int it = tid; it < NGN * KK; it += 256) {
        const int nl = it >> 9;           // it / 512
        const int k  = it & (KK - 1);
        const int n  = n0 + nl;
        const int bn = b * NDEP + n;

        const float4 dep = ((const float4*)ed)[bn];   // x,y,z,E (16B aligned)
        const float nval  = dep.w * (1000000.0f / 22.4f);
        const float sigma = sqrtf(0.15f * nval);
        int ne = (int)(sigma * edraw[bn] + nval);     // trunc toward zero, matches astype(int32)
        ne = min(max(ne, 0), KK);
        if (k >= ne) continue;                        // slot_mask

        const float sqz = sqrtf(dep.z);
        const float* dd = ddraw + ((size_t)bn * KK + k) * 3;
        const float ez  = sD2[2] * dd[2] * sqz + dep.z;
        const float prob = 1.0f - __expf(-ez * invLife);
        if (!(prob > udraw[(size_t)bn * KK + k])) continue;   // survival mask

        const float ex = sD2[0] * dd[0] * sqz + dep.x;
        const float ey = sD2[1] * dd[1] * sqz + dep.y;

        // MLP: h = sigmoid(xy @ W1 + b1); pmt = sigmoid(h @ W2 + b2) * scale^2
        float pm[NP];
        #pragma unroll
        for (int p = 0; p < NP; ++p) pm[p] = sb2[p];
        #pragma unroll 4
        for (int j = 0; j < 28; ++j) {
            float hj = fmaf(sW1[j], ex, fmaf(sW1[28 + j], ey, sb1[j]));
            hj = 1.0f / (1.0f + __expf(-hj));
            #pragma unroll
            for (int p = 0; p < NP; ++p) pm[p] = fmaf(hj, sW2[j * NP + p], pm[p]);
        }
        #pragma unroll
        for (int p = 0; p < NP; ++p) pm[p] = sS2[p] / (1.0f + __expf(-pm[p]));

        // Windowed Gaussian scatter: only ticks within ~|3| of z_e matter.
        const int t0 = (int)floorf(ez) - 3;
        #pragma unroll
        for (int dt = 0; dt < 7; ++dt) {
            const int t = t0 + dt;
            if ((unsigned)t < (unsigned)NT) {
                const float d = ((float)t + 0.5f) - ez;
                const float g = 3.9894228040143274f * __expf(-10.0f * d * d);
                float* row = &acc[t * NP];
                #pragma unroll
                for (int p = 0; p < NP; ++p) atomicAdd(&row[p], pm[p] * g);
            }
        }
    }
    __syncthreads();

    // Sparse writeback: out is (b, p, t); acc is [t][p]. Skip untouched entries.
    float* outB = out + (size_t)b * NP * NT;
    for (int idx = tid; idx < NP * NT; idx += 256) {
        const int p = idx / NT;
        const int t = idx - p * NT;
        const float v = acc[t * NP + p];
        if (v != 0.0f) atomicAdd(&outB[idx], v);
    }
}

extern "C" void kernel_launch(void* const* d_in, const int* in_sizes, int n_in,
                              void* d_out, int out_size, void* d_ws, size_t ws_size,
                              hipStream_t stream) {
    const float* ed     = (const float*)d_in[0];
    const float* edraw  = (const float*)d_in[1];
    const float* ddraw  = (const float*)d_in[2];
    const float* udraw  = (const float*)d_in[3];
    const float* W1     = (const float*)d_in[4];
    const float* b1     = (const float*)d_in[5];
    const float* W2     = (const float*)d_in[6];
    const float* b2     = (const float*)d_in[7];
    const float* dscale = (const float*)d_in[8];
    const float* pscale = (const float*)d_in[9];
    const float* life   = (const float*)d_in[10];
    float* out = (float*)d_out;

    hipMemsetAsync(d_out, 0, (size_t)out_size * sizeof(float), stream);
    next_sim_kernel<<<NB * (NDEP / NGN), 256, 0, stream>>>(
        ed, edraw, ddraw, udraw, W1, b1, W2, b2, dscale, pscale, life, out);
}

// Round 3
// 26.131 us; speedup vs baseline: 5.5138x; 5.5138x over previous
//
#include <hip/hip_runtime.h>

#define NB     8
#define NDEP   64
#define KK     512
#define NP     12
#define NT     550
#define KSPLIT 2
#define KCH    (KK / KSPLIT)   // 256 k's per block
#define WIN    32              // tick window per n, centered on floor(z)
#define PST    16              // pm_lds row stride (floats): 64B, b128-aligned

__global__ __launch_bounds__(256) void next_sim_kernel(
    const float* __restrict__ ed,      // (8,64,4) x,y,z,E
    const float* __restrict__ edraw,   // (8,64)
    const float* __restrict__ ddraw,   // (8,64,512,3)
    const float* __restrict__ udraw,   // (8,64,512)
    const float* __restrict__ W1,      // (2,28)
    const float* __restrict__ b1,      // (28)
    const float* __restrict__ W2,      // (28,12)
    const float* __restrict__ b2,      // (12)
    const float* __restrict__ dscale,  // (3)
    const float* __restrict__ pscale,  // (12)
    const float* __restrict__ life,    // (1)
    float* __restrict__ out)           // (8,12,550)
{
    __shared__ float pm_lds[KCH * PST];   // 16 KB; reused as reduction buffer
    __shared__ float ez_lds[KCH];
    __shared__ float sW1[56], sb1[28], sW2[336], sb2[12], sS2[12], sD2[3];

    const int tid = threadIdx.x;
    const int bid = blockIdx.x;
    const int b   = bid / (NDEP * KSPLIT);
    const int rem = bid % (NDEP * KSPLIT);
    const int n   = rem / KSPLIT;
    const int ks  = rem % KSPLIT;
    const int bn  = b * NDEP + n;

    for (int i = tid; i < 336; i += 256) sW2[i] = W2[i];
    if (tid < 56) sW1[tid] = W1[tid];
    if (tid < 28) sb1[tid] = b1[tid];
    if (tid < 12) sb2[tid] = b2[tid];
    if (tid < 12) { float s = pscale[tid]; sS2[tid] = s * s; }
    if (tid < 3)  { float s = dscale[tid]; sD2[tid] = s * s; }
    __syncthreads();

    const float4 dep  = ((const float4*)ed)[bn];   // x,y,z,E
    const float nval  = dep.w * (1000000.0f / 22.4f);
    const float sigma = sqrtf(0.15f * nval);
    int ne = (int)(sigma * edraw[bn] + nval);      // trunc toward 0 == astype(int32)
    ne = min(max(ne, 0), KK);
    const float sqz     = sqrtf(dep.z);
    const float invLife = 1.0f / life[0];
    const int   t_base  = (int)floorf(dep.z) - WIN / 2;   // in [34, 484]: always in-bounds

    // ---- phase 1: per-k masked pm[12] and ez into LDS (no atomics, branchless)
    {
        const int kk = ks * KCH + tid;
        const float* dd = ddraw + ((size_t)bn * KK + kk) * 3;
        const float d0 = dd[0], d1 = dd[1], d2 = dd[2];
        const float ez = fmaf(sD2[2] * d2, sqz, dep.z);
        const float ex = fmaf(sD2[0] * d0, sqz, dep.x);
        const float ey = fmaf(sD2[1] * d1, sqz, dep.y);
        const float prob = 1.0f - __expf(-ez * invLife);
        const float m = ((kk < ne) && (prob > udraw[(size_t)bn * KK + kk])) ? 1.0f : 0.0f;

        float pm[NP];
        #pragma unroll
        for (int p = 0; p < NP; ++p) pm[p] = sb2[p];
        #pragma unroll 4
        for (int j = 0; j < 28; ++j) {
            float hj = fmaf(sW1[j], ex, fmaf(sW1[28 + j], ey, sb1[j]));
            hj = 1.0f / (1.0f + __expf(-hj));
            #pragma unroll
            for (int p = 0; p < NP; ++p) pm[p] = fmaf(hj, sW2[j * NP + p], pm[p]);
        }
        #pragma unroll
        for (int p = 0; p < NP; ++p) pm[p] = m * sS2[p] / (1.0f + __expf(-pm[p]));

        ez_lds[tid] = ez;
        float4* prow = (float4*)&pm_lds[tid * PST];
        prow[0] = make_float4(pm[0], pm[1], pm[2],  pm[3]);
        prow[1] = make_float4(pm[4], pm[5], pm[6],  pm[7]);
        prow[2] = make_float4(pm[8], pm[9], pm[10], pm[11]);
    }
    __syncthreads();

    // ---- phase 2: dense gather. thread = (t_rel, k-chunk); reads are wave-uniform (broadcast)
    const int   tw    = tid & (WIN - 1);
    const int   chunk = tid >> 5;                 // 0..7, 32 k's each
    const float tc    = (float)(t_base + tw) + 0.5f;
    float4 a0 = {0,0,0,0}, a1 = {0,0,0,0}, a2 = {0,0,0,0};
    #pragma unroll 4
    for (int i = 0; i < KCH / 8; ++i) {
        const int   k = chunk * (KCH / 8) + i;
        const float d = tc - ez_lds[k];
        const float g = 3.9894228040143274f * __expf(-10.0f * d * d);  // 0 outside window
        const float4* prow = (const float4*)&pm_lds[k * PST];
        const float4 p0 = prow[0], p1 = prow[1], p2 = prow[2];
        a0.x = fmaf(p0.x, g, a0.x); a0.y = fmaf(p0.y, g, a0.y);
        a0.z = fmaf(p0.z, g, a0.z); a0.w = fmaf(p0.w, g, a0.w);
        a1.x = fmaf(p1.x, g, a1.x); a1.y = fmaf(p1.y, g, a1.y);
        a1.z = fmaf(p1.z, g, a1.z); a1.w = fmaf(p1.w, g, a1.w);
        a2.x = fmaf(p2.x, g, a2.x); a2.y = fmaf(p2.y, g, a2.y);
        a2.z = fmaf(p2.z, g, a2.z); a2.w = fmaf(p2.w, g, a2.w);
    }
    __syncthreads();
    {   // park partials (row index == tid, since tid = chunk*32 + tw)
        float4* rrow = (float4*)&pm_lds[tid * PST];
        rrow[0] = a0; rrow[1] = a1; rrow[2] = a2;
    }
    __syncthreads();

    // ---- phase 3: reduce 8 chunk-partials, sparse-window global writeback
    float* outB = out + (size_t)b * NP * NT;
    for (int idx = tid; idx < WIN * NP; idx += 256) {
        const int t_rel = idx / NP;
        const int p     = idx - t_rel * NP;
        float s = 0.0f;
        #pragma unroll
        for (int c = 0; c < 8; ++c) s += pm_lds[(c * WIN + t_rel) * PST + p];
        atomicAdd(&outB[p * NT + (t_base + t_rel)], s);
    }
}

extern "C" void kernel_launch(void* const* d_in, const int* in_sizes, int n_in,
                              void* d_out, int out_size, void* d_ws, size_t ws_size,
                              hipStream_t stream) {
    const float* ed     = (const float*)d_in[0];
    const float* edraw  = (const float*)d_in[1];
    const float* ddraw  = (const float*)d_in[2];
    const float* udraw  = (const float*)d_in[3];
    const float* W1     = (const float*)d_in[4];
    const float* b1     = (const float*)d_in[5];
    const float* W2     = (const float*)d_in[6];
    const float* b2     = (const float*)d_in[7];
    const float* dscale = (const float*)d_in[8];
    const float* pscale = (const float*)d_in[9];
    const float* life   = (const float*)d_in[10];
    float* out = (float*)d_out;

    hipMemsetAsync(d_out, 0, (size_t)out_size * sizeof(float), stream);
    next_sim_kernel<<<NB * NDEP * KSPLIT, 256, 0, stream>>>(
        ed, edraw, ddraw, udraw, W1, b1, W2, b2, dscale, pscale, life, out);
}